// Round 1
// baseline (2576.970 us; speedup 1.0000x reference)
//
#include <hip/hip_runtime.h>

// Problem constants (fixed by the reference):
static constexpr int BATCH = 16;
static constexpr int NNODE = 4096;
static constexpr int NEDGE = 65536;            // 1 << 16
static constexpr int ROWS  = BATCH * NNODE;    // 65536

#define BM 64
#define BN 64
#define BK 16

// h = X @ W, then zero rows whose node is masked out.
// X: [M, K], W: [K, Nd], H: [M, Nd], mask: [M]
__global__ __launch_bounds__(256) void gemm_mask_kernel(
    const float* __restrict__ X, const float* __restrict__ W,
    const int* __restrict__ mask, float* __restrict__ H,
    int M, int K, int Nd)
{
    __shared__ float As[BK][BM + 4];   // +4 pad: conflict-free transposed store, 16B-aligned rows
    __shared__ float Bs[BK][BN];

    const int bm  = blockIdx.y * BM;
    const int bn  = blockIdx.x * BN;
    const int tid = threadIdx.x;
    const int tx  = tid & 15;   // 16 col-groups
    const int ty  = tid >> 4;   // 16 row-groups

    float acc[4][4] = {};

    for (int k0 = 0; k0 < K; k0 += BK) {
        // Stage X tile (BM x BK), transposed into As[k][m]
        #pragma unroll
        for (int i = tid; i < BM * BK; i += 256) {
            int r = i >> 4;          // / BK
            int c = i & 15;          // % BK
            As[c][r] = X[(size_t)(bm + r) * K + (k0 + c)];
        }
        // Stage W tile (BK x BN)
        #pragma unroll
        for (int i = tid; i < BK * BN; i += 256) {
            int r = i >> 6;          // / BN
            int c = i & 63;          // % BN
            Bs[r][c] = W[(size_t)(k0 + r) * Nd + (bn + c)];
        }
        __syncthreads();

        #pragma unroll
        for (int kk = 0; kk < BK; ++kk) {
            float4 a4 = *(const float4*)&As[kk][ty * 4];
            float4 b4 = *(const float4*)&Bs[kk][tx * 4];
            float av[4] = {a4.x, a4.y, a4.z, a4.w};
            float bv[4] = {b4.x, b4.y, b4.z, b4.w};
            #pragma unroll
            for (int i = 0; i < 4; ++i)
                #pragma unroll
                for (int j = 0; j < 4; ++j)
                    acc[i][j] += av[i] * bv[j];
        }
        __syncthreads();
    }

    #pragma unroll
    for (int i = 0; i < 4; ++i) {
        int row = bm + ty * 4 + i;
        float m = (mask[row] > 0) ? 1.0f : 0.0f;
        float4 o;
        o.x = acc[i][0] * m;
        o.y = acc[i][1] * m;
        o.z = acc[i][2] * m;
        o.w = acc[i][3] * m;
        *(float4*)&H[(size_t)row * Nd + bn + tx * 4] = o;
    }
}

// One wave per edge: agg[v] += w * h[u], skipped (wave-uniform) if either
// endpoint is masked out (75% of edges!).
template<int D>
__global__ __launch_bounds__(256) void scatter_kernel(
    const int* __restrict__ ei, const float* __restrict__ ew,
    const int* __restrict__ mask, const float* __restrict__ H,
    float* __restrict__ AGG)
{
    const int gid  = blockIdx.x * 256 + threadIdx.x;
    const int wave = gid >> 6;
    const int lane = gid & 63;
    const int b = wave >> 16;            // NEDGE == 1<<16
    const int e = wave & (NEDGE - 1);

    const int* eib = ei + (size_t)b * 2 * NEDGE;
    const int u = eib[e];
    const int v = eib[NEDGE + e];
    const int mrow = b * NNODE;
    if (mask[mrow + u] == 0 || mask[mrow + v] == 0) return;

    const float w = ew[(size_t)b * NEDGE + e];
    const float* hu = H   + (size_t)(mrow + u) * D;
    float*       av = AGG + (size_t)(mrow + v) * D;

    if constexpr (D == 256) {
        float4 h = ((const float4*)hu)[lane];
        atomicAdd(av + lane * 4 + 0, w * h.x);
        atomicAdd(av + lane * 4 + 1, w * h.y);
        atomicAdd(av + lane * 4 + 2, w * h.z);
        atomicAdd(av + lane * 4 + 3, w * h.w);
    } else {
        float2 h = ((const float2*)hu)[lane];
        atomicAdd(av + lane * 2 + 0, w * h.x);
        atomicAdd(av + lane * 2 + 1, w * h.y);
    }
}

// out = valid ? relu(agg + bias) : 0   (vectorized float4; in-place safe)
template<int D>
__global__ __launch_bounds__(256) void epilogue_kernel(
    const float* __restrict__ AGG, const int* __restrict__ mask,
    const float* __restrict__ bias, float* __restrict__ OUT)
{
    constexpr int D4 = D / 4;
    const size_t idx = (size_t)blockIdx.x * 256 + threadIdx.x;  // one float4
    const size_t total4 = (size_t)ROWS * D4;
    if (idx >= total4) return;
    const size_t row = idx / D4;
    const int    c4  = (int)(idx % D4);

    float4 a = ((const float4*)AGG)[idx];
    if (mask[row] > 0) {
        float4 bb = ((const float4*)bias)[c4];
        a.x = fmaxf(a.x + bb.x, 0.0f);
        a.y = fmaxf(a.y + bb.y, 0.0f);
        a.z = fmaxf(a.z + bb.z, 0.0f);
        a.w = fmaxf(a.w + bb.w, 0.0f);
    } else {
        a.x = a.y = a.z = a.w = 0.0f;
    }
    ((float4*)OUT)[idx] = a;
}

extern "C" void kernel_launch(void* const* d_in, const int* in_sizes, int n_in,
                              void* d_out, int out_size, void* d_ws, size_t ws_size,
                              hipStream_t stream) {
    const float* x    = (const float*)d_in[0];   // [16, 4096, 128]
    const int*   ei   = (const int*)  d_in[1];   // [16, 2, 65536]
    const float* ew   = (const float*)d_in[2];   // [16, 65536]
    const int*   mask = (const int*)  d_in[3];   // [16, 4096]
    const float* W1   = (const float*)d_in[4];   // [128, 256]
    const float* b1   = (const float*)d_in[5];
    const float* W2   = (const float*)d_in[6];   // [256, 256]
    const float* b2   = (const float*)d_in[7];
    const float* W3   = (const float*)d_in[8];   // [256, 128]
    const float* b3   = (const float*)d_in[9];
    float* out = (float*)d_out;                  // [16, 4096, 128]

    // Two 64 MiB ping-pong regions (ROWS * 256 floats each).
    const size_t REGION = (size_t)ROWS * 256 * sizeof(float);   // 67,108,864 B
    float* A = (float*)d_ws;
    float* Bf = (float*)((char*)d_ws + REGION);

    const int M = ROWS;
    const dim3 blk(256);
    const int scatterBlocks = (BATCH * NEDGE * 64) / 256;        // 262,144
    const int epi256Blocks  = (ROWS * 64 + 255) / 256;           // 16,384 (float4s)
    const int epi128Blocks  = (ROWS * 32 + 255) / 256;           // 8,192

    // ---- Layer 1: 128 -> 256 ----
    gemm_mask_kernel<<<dim3(256 / BN, M / BM), blk, 0, stream>>>(x, W1, mask, A, M, 128, 256);
    hipMemsetAsync(Bf, 0, REGION, stream);
    scatter_kernel<256><<<scatterBlocks, blk, 0, stream>>>(ei, ew, mask, A, Bf);
    epilogue_kernel<256><<<epi256Blocks, blk, 0, stream>>>(Bf, mask, b1, A);   // x2 -> A

    // ---- Layer 2: 256 -> 256 ----
    gemm_mask_kernel<<<dim3(256 / BN, M / BM), blk, 0, stream>>>(A, W2, mask, Bf, M, 256, 256);
    hipMemsetAsync(A, 0, REGION, stream);
    scatter_kernel<256><<<scatterBlocks, blk, 0, stream>>>(ei, ew, mask, Bf, A);
    epilogue_kernel<256><<<epi256Blocks, blk, 0, stream>>>(A, mask, b2, Bf);   // x3 -> Bf

    // ---- Layer 3: 256 -> 128 ----
    gemm_mask_kernel<<<dim3(128 / BN, M / BM), blk, 0, stream>>>(Bf, W3, mask, A, M, 256, 128);
    hipMemsetAsync(out, 0, (size_t)ROWS * 128 * sizeof(float), stream);
    scatter_kernel<128><<<scatterBlocks, blk, 0, stream>>>(ei, ew, mask, A, out);
    epilogue_kernel<128><<<epi128Blocks, blk, 0, stream>>>(out, mask, b3, out);
}

// Round 2
// 528.850 us; speedup vs baseline: 4.8728x; 4.8728x over previous
//
#include <hip/hip_runtime.h>

static constexpr int BATCH = 16;
static constexpr int NNODE = 4096;
static constexpr int NEDGE = 65536;            // 1 << 16
static constexpr int ROWS  = BATCH * NNODE;    // 65536

#define BM 64
#define BN 64
#define BK 16

typedef _Float16 half4v __attribute__((ext_vector_type(4)));
typedef _Float16 half2v __attribute__((ext_vector_type(2)));

// ---------------- CSR build (once; reused by all 3 layers) ----------------

// counts[b][v] = # of valid edges into v
__global__ __launch_bounds__(256) void count_kernel(
    const int* __restrict__ ei, const int* __restrict__ mask,
    int* __restrict__ counts)
{
    const int idx = blockIdx.x * 256 + threadIdx.x;   // [0, BATCH*NEDGE)
    const int b = idx >> 16;
    const int e = idx & (NEDGE - 1);
    const int* eib = ei + (size_t)b * 2 * NEDGE;
    const int u = eib[e];
    const int v = eib[NEDGE + e];
    const int mrow = b * NNODE;
    if (mask[mrow + u] != 0 && mask[mrow + v] != 0)
        atomicAdd(&counts[mrow + v], 1);
}

// Exclusive scan of counts[b][0..4095] -> row_start[b][0..4096]; cursor copy.
__global__ __launch_bounds__(256) void scan_kernel(
    const int* __restrict__ counts, int* __restrict__ row_start,
    int* __restrict__ cursor)
{
    __shared__ int sums[256];
    const int b = blockIdx.x, t = threadIdx.x;
    const int* c = counts + b * NNODE;
    int* rs = row_start + b * (NNODE + 1);
    int* cu = cursor + b * NNODE;

    int local[16]; int s = 0;
    #pragma unroll
    for (int i = 0; i < 16; ++i) { local[i] = c[t * 16 + i]; s += local[i]; }
    sums[t] = s;
    __syncthreads();
    for (int off = 1; off < 256; off <<= 1) {
        int v = (t >= off) ? sums[t - off] : 0;
        __syncthreads();
        sums[t] += v;
        __syncthreads();
    }
    int run = (t == 0) ? 0 : sums[t - 1];
    #pragma unroll
    for (int i = 0; i < 16; ++i) { rs[t * 16 + i] = run; cu[t * 16 + i] = run; run += local[i]; }
    if (t == 255) rs[NNODE] = run;
}

// bkt[b][pos] = (bits(w) << 32) | u for valid edges
__global__ __launch_bounds__(256) void fill_kernel(
    const int* __restrict__ ei, const float* __restrict__ ew,
    const int* __restrict__ mask, int* __restrict__ cursor,
    unsigned long long* __restrict__ bkt)
{
    const int idx = blockIdx.x * 256 + threadIdx.x;
    const int b = idx >> 16;
    const int e = idx & (NEDGE - 1);
    const int* eib = ei + (size_t)b * 2 * NEDGE;
    const int u = eib[e];
    const int v = eib[NEDGE + e];
    const int mrow = b * NNODE;
    if (mask[mrow + u] != 0 && mask[mrow + v] != 0) {
        const float w = ew[(size_t)b * NEDGE + e];
        const int pos = atomicAdd(&cursor[mrow + v], 1);
        bkt[(size_t)b * NEDGE + pos] =
            ((unsigned long long)__float_as_uint(w) << 32) | (unsigned)u;
    }
}

// ---------------- h = X @ W (fp32 in, fp16 out) ----------------
__global__ __launch_bounds__(256) void gemm_kernel(
    const float* __restrict__ X, const float* __restrict__ W,
    _Float16* __restrict__ H, int K, int Nd)
{
    __shared__ float As[BK][BM + 4];
    __shared__ float Bs[BK][BN];

    const int bm  = blockIdx.y * BM;
    const int bn  = blockIdx.x * BN;
    const int tid = threadIdx.x;
    const int tx  = tid & 15;
    const int ty  = tid >> 4;

    float acc[4][4] = {};

    for (int k0 = 0; k0 < K; k0 += BK) {
        #pragma unroll
        for (int i = tid; i < BM * BK; i += 256) {
            int r = i >> 4;
            int c = i & 15;
            As[c][r] = X[(size_t)(bm + r) * K + (k0 + c)];
        }
        #pragma unroll
        for (int i = tid; i < BK * BN; i += 256) {
            int r = i >> 6;
            int c = i & 63;
            Bs[r][c] = W[(size_t)(k0 + r) * Nd + (bn + c)];
        }
        __syncthreads();

        #pragma unroll
        for (int kk = 0; kk < BK; ++kk) {
            float4 a4 = *(const float4*)&As[kk][ty * 4];
            float4 b4 = *(const float4*)&Bs[kk][tx * 4];
            float av[4] = {a4.x, a4.y, a4.z, a4.w};
            float bv[4] = {b4.x, b4.y, b4.z, b4.w};
            #pragma unroll
            for (int i = 0; i < 4; ++i)
                #pragma unroll
                for (int j = 0; j < 4; ++j)
                    acc[i][j] += av[i] * bv[j];
        }
        __syncthreads();
    }

    #pragma unroll
    for (int i = 0; i < 4; ++i) {
        int row = bm + ty * 4 + i;
        half4v o;
        #pragma unroll
        for (int j = 0; j < 4; ++j) o[j] = (_Float16)acc[i][j];
        *(half4v*)&H[(size_t)row * Nd + bn + tx * 4] = o;
    }
}

// ---------------- gather + bias + relu + mask (one wave per node) ----------
template<int D>
__global__ __launch_bounds__(256) void gather_kernel(
    const int* __restrict__ row_start, const unsigned long long* __restrict__ bkt,
    const _Float16* __restrict__ H, const int* __restrict__ mask,
    const float* __restrict__ bias, float* __restrict__ OUT)
{
    constexpr int PER = D / 64;                 // floats per lane (4 or 2)
    const int gw   = blockIdx.x * 4 + (threadIdx.x >> 6);
    const int lane = threadIdx.x & 63;
    const int b = gw >> 12;                     // 4096 nodes/batch
    const int n = gw & (NNODE - 1);
    const int mrow = b * NNODE + n;

    float acc[PER] = {};
    if (mask[mrow] != 0) {
        const int* rs = row_start + b * (NNODE + 1);
        const int s = rs[n], e = rs[n + 1];
        const unsigned long long* bk = bkt + (size_t)b * NEDGE;
        for (int i = s; i < e; ++i) {
            const unsigned long long pk = bk[i];
            const int u = (int)(pk & 0xffffffffu);
            const float w = __uint_as_float((unsigned)(pk >> 32));
            const _Float16* hr = H + ((size_t)(b * NNODE + u) * D) + lane * PER;
            if constexpr (PER == 4) {
                half4v hv = *(const half4v*)hr;
                #pragma unroll
                for (int j = 0; j < 4; ++j) acc[j] += w * (float)hv[j];
            } else {
                half2v hv = *(const half2v*)hr;
                #pragma unroll
                for (int j = 0; j < 2; ++j) acc[j] += w * (float)hv[j];
            }
        }
        #pragma unroll
        for (int j = 0; j < PER; ++j)
            acc[j] = fmaxf(acc[j] + bias[lane * PER + j], 0.0f);
    }

    float* op = OUT + (size_t)mrow * D + lane * PER;
    if constexpr (PER == 4) {
        float4 o = {acc[0], acc[1], acc[2], acc[3]};
        *(float4*)op = o;
    } else {
        float2 o = {acc[0], acc[1]};
        *(float2*)op = o;
    }
}

extern "C" void kernel_launch(void* const* d_in, const int* in_sizes, int n_in,
                              void* d_out, int out_size, void* d_ws, size_t ws_size,
                              hipStream_t stream) {
    const float* x    = (const float*)d_in[0];
    const int*   ei   = (const int*)  d_in[1];
    const float* ew   = (const float*)d_in[2];
    const int*   mask = (const int*)  d_in[3];
    const float* W1   = (const float*)d_in[4];
    const float* b1   = (const float*)d_in[5];
    const float* W2   = (const float*)d_in[6];
    const float* b2   = (const float*)d_in[7];
    const float* W3   = (const float*)d_in[8];
    const float* b3   = (const float*)d_in[9];
    float* out = (float*)d_out;

    // Workspace layout (~105 MB):
    char* ws = (char*)d_ws;
    _Float16* Hbuf = (_Float16*)ws;                                  // 32 MB
    float*    Act  = (float*)(ws + (size_t)ROWS * 256 * 2);          // 64 MB
    unsigned long long* bkt =
        (unsigned long long*)(ws + (size_t)ROWS * 256 * 2 + (size_t)ROWS * 256 * 4); // 8 MB
    int* counts    = (int*)((char*)bkt + (size_t)BATCH * NEDGE * 8); // 256 KB
    int* row_start = counts + BATCH * NNODE;                         // 16*(4097)
    int* cursor    = row_start + BATCH * (NNODE + 1);                // 256 KB

    const dim3 blk(256);
    const int edgeBlocks   = BATCH * NEDGE / 256;   // 4096
    const int gatherBlocks = ROWS / 4;              // 16384 (4 waves/block)

    // ---- CSR build (layer-invariant) ----
    hipMemsetAsync(counts, 0, (size_t)BATCH * NNODE * sizeof(int), stream);
    count_kernel<<<edgeBlocks, blk, 0, stream>>>(ei, mask, counts);
    scan_kernel<<<BATCH, blk, 0, stream>>>(counts, row_start, cursor);
    fill_kernel<<<edgeBlocks, blk, 0, stream>>>(ei, ew, mask, cursor, bkt);

    // ---- Layer 1: 128 -> 256 ----
    gemm_kernel<<<dim3(256 / BN, ROWS / BM), blk, 0, stream>>>(x, W1, Hbuf, 128, 256);
    gather_kernel<256><<<gatherBlocks, blk, 0, stream>>>(row_start, bkt, Hbuf, mask, b1, Act);

    // ---- Layer 2: 256 -> 256 ----
    gemm_kernel<<<dim3(256 / BN, ROWS / BM), blk, 0, stream>>>(Act, W2, Hbuf, 256, 256);
    gather_kernel<256><<<gatherBlocks, blk, 0, stream>>>(row_start, bkt, Hbuf, mask, b2, Act);

    // ---- Layer 3: 256 -> 128 ----
    gemm_kernel<<<dim3(128 / BN, ROWS / BM), blk, 0, stream>>>(Act, W3, Hbuf, 256, 128);
    gather_kernel<128><<<gatherBlocks, blk, 0, stream>>>(row_start, bkt, Hbuf, mask, b3, out);
}

// Round 3
// 316.550 us; speedup vs baseline: 8.1408x; 1.6707x over previous
//
#include <hip/hip_runtime.h>

static constexpr int BATCH = 16;
static constexpr int NNODE = 4096;
static constexpr int NEDGE = 65536;            // 1 << 16
static constexpr int ROWS  = BATCH * NNODE;    // 65536

typedef _Float16 half8  __attribute__((ext_vector_type(8)));
typedef _Float16 half4v __attribute__((ext_vector_type(4)));
typedef _Float16 half2v __attribute__((ext_vector_type(2)));
typedef float    f32x4  __attribute__((ext_vector_type(4)));

// ---------------- CSR build (once; reused by all 3 layers) ----------------

__global__ __launch_bounds__(256) void count_kernel(
    const int* __restrict__ ei, const int* __restrict__ mask,
    int* __restrict__ counts)
{
    const int idx = blockIdx.x * 256 + threadIdx.x;
    const int b = idx >> 16;
    const int e = idx & (NEDGE - 1);
    const int* eib = ei + (size_t)b * 2 * NEDGE;
    const int u = eib[e];
    const int v = eib[NEDGE + e];
    const int mrow = b * NNODE;
    if (mask[mrow + u] != 0 && mask[mrow + v] != 0)
        atomicAdd(&counts[mrow + v], 1);
}

__global__ __launch_bounds__(256) void scan_kernel(
    const int* __restrict__ counts, int* __restrict__ row_start,
    int* __restrict__ cursor)
{
    __shared__ int sums[256];
    const int b = blockIdx.x, t = threadIdx.x;
    const int* c = counts + b * NNODE;
    int* rs = row_start + b * (NNODE + 1);
    int* cu = cursor + b * NNODE;

    int local[16]; int s = 0;
    #pragma unroll
    for (int i = 0; i < 16; ++i) { local[i] = c[t * 16 + i]; s += local[i]; }
    sums[t] = s;
    __syncthreads();
    for (int off = 1; off < 256; off <<= 1) {
        int v = (t >= off) ? sums[t - off] : 0;
        __syncthreads();
        sums[t] += v;
        __syncthreads();
    }
    int run = (t == 0) ? 0 : sums[t - 1];
    #pragma unroll
    for (int i = 0; i < 16; ++i) { rs[t * 16 + i] = run; cu[t * 16 + i] = run; run += local[i]; }
    if (t == 255) rs[NNODE] = run;
}

__global__ __launch_bounds__(256) void fill_kernel(
    const int* __restrict__ ei, const float* __restrict__ ew,
    const int* __restrict__ mask, int* __restrict__ cursor,
    unsigned long long* __restrict__ bkt)
{
    const int idx = blockIdx.x * 256 + threadIdx.x;
    const int b = idx >> 16;
    const int e = idx & (NEDGE - 1);
    const int* eib = ei + (size_t)b * 2 * NEDGE;
    const int u = eib[e];
    const int v = eib[NEDGE + e];
    const int mrow = b * NNODE;
    if (mask[mrow + u] != 0 && mask[mrow + v] != 0) {
        const float w = ew[(size_t)b * NEDGE + e];
        const int pos = atomicAdd(&cursor[mrow + v], 1);
        bkt[(size_t)b * NEDGE + pos] =
            ((unsigned long long)__float_as_uint(w) << 32) | (unsigned)u;
    }
}

// ---------------- dtype prep ----------------

__global__ __launch_bounds__(256) void cast_x_kernel(
    const float* __restrict__ X, _Float16* __restrict__ X16, int n4)
{
    int i = blockIdx.x * 256 + threadIdx.x;
    if (i < n4) {
        float4 v = ((const float4*)X)[i];
        half4v h = {(_Float16)v.x, (_Float16)v.y, (_Float16)v.z, (_Float16)v.w};
        ((half4v*)X16)[i] = h;
    }
}

// W [K][Nd] fp32 -> Wt [Nd][K] fp16
__global__ __launch_bounds__(256) void wt_kernel(
    const float* __restrict__ W, _Float16* __restrict__ Wt, int K, int Nd)
{
    int i = blockIdx.x * 256 + threadIdx.x;
    if (i < K * Nd) {
        int k = i / Nd, n = i - k * Nd;
        Wt[n * K + k] = (_Float16)W[i];
    }
}

// ---------------- H = X @ Wt^T  (fp16 in, fp32 acc, fp16 out) ----------------
// 128x128 tile, BK=32, 4 waves of 64x64, mfma_f32_16x16x32_f16.
template<int K>
__global__ __launch_bounds__(256) void gemm_mfma(
    const _Float16* __restrict__ X,   // [M, K]
    const _Float16* __restrict__ Wt,  // [Nd, K]
    _Float16* __restrict__ H,         // [M, Nd]
    int Nd)
{
    __shared__ _Float16 As[128 * 32];   // [m][k] row-major
    __shared__ _Float16 Bs[128 * 32];   // [n][k] row-major

    const int tid  = threadIdx.x;
    const int lane = tid & 63;
    const int wave = tid >> 6;
    const int wr = wave >> 1, wc = wave & 1;
    const int quad = lane >> 4;
    const int l15  = lane & 15;

    const size_t bm = (size_t)blockIdx.y * 128;
    const int    bn = blockIdx.x * 128;

    f32x4 acc[4][4] = {};

    // Staging: thread t covers (row = t>>2, 16B chunk = t&3); LDS dest = base + tid*16B. [m104 rule]
    const int sr = tid >> 2;
    const int sc = (tid & 3) * 8;
    const _Float16* Ag0 = X  + (bm + sr) * K + sc;
    const _Float16* Ag1 = X  + (bm + 64 + sr) * K + sc;
    const _Float16* Bg0 = Wt + (size_t)(bn + sr) * K + sc;
    const _Float16* Bg1 = Wt + (size_t)(bn + 64 + sr) * K + sc;

    const _Float16* ap = As + (wr * 64 + l15) * 32 + quad * 8;
    const _Float16* bp = Bs + (wc * 64 + l15) * 32 + quad * 8;

    for (int k0 = 0; k0 < K; k0 += 32) {
        __builtin_amdgcn_global_load_lds(
            (const __attribute__((address_space(1))) void*)(Ag0 + k0),
            (__attribute__((address_space(3))) void*)(As + tid * 8), 16, 0, 0);
        __builtin_amdgcn_global_load_lds(
            (const __attribute__((address_space(1))) void*)(Ag1 + k0),
            (__attribute__((address_space(3))) void*)(As + 2048 + tid * 8), 16, 0, 0);
        __builtin_amdgcn_global_load_lds(
            (const __attribute__((address_space(1))) void*)(Bg0 + k0),
            (__attribute__((address_space(3))) void*)(Bs + tid * 8), 16, 0, 0);
        __builtin_amdgcn_global_load_lds(
            (const __attribute__((address_space(1))) void*)(Bg1 + k0),
            (__attribute__((address_space(3))) void*)(Bs + 2048 + tid * 8), 16, 0, 0);
        __syncthreads();

        half8 af[4], bf[4];
        #pragma unroll
        for (int mi = 0; mi < 4; ++mi) af[mi] = *(const half8*)(ap + mi * 16 * 32);
        #pragma unroll
        for (int ni = 0; ni < 4; ++ni) bf[ni] = *(const half8*)(bp + ni * 16 * 32);

        #pragma unroll
        for (int mi = 0; mi < 4; ++mi)
            #pragma unroll
            for (int ni = 0; ni < 4; ++ni)
                acc[mi][ni] = __builtin_amdgcn_mfma_f32_16x16x32_f16(
                    af[mi], bf[ni], acc[mi][ni], 0, 0, 0);
        __syncthreads();
    }

    // C/D layout: col = lane&15, row = quad*4 + r  [m89]
    const size_t rbase = bm + wr * 64 + quad * 4;
    const int    cbase = bn + wc * 64 + l15;
    #pragma unroll
    for (int mi = 0; mi < 4; ++mi)
        #pragma unroll
        for (int r = 0; r < 4; ++r) {
            size_t row = rbase + mi * 16 + r;
            #pragma unroll
            for (int ni = 0; ni < 4; ++ni)
                H[row * Nd + cbase + ni * 16] = (_Float16)acc[mi][ni][r];
        }
}

// ---------------- gather + bias + relu + mask (one wave per node) ----------
template<int D, typename OT>
__global__ __launch_bounds__(256) void gather_kernel(
    const int* __restrict__ row_start, const unsigned long long* __restrict__ bkt,
    const _Float16* __restrict__ H, const int* __restrict__ mask,
    const float* __restrict__ bias, OT* __restrict__ OUT)
{
    constexpr int PER = D / 64;
    const int gw   = blockIdx.x * 4 + (threadIdx.x >> 6);
    const int lane = threadIdx.x & 63;
    const int b = gw >> 12;
    const int n = gw & (NNODE - 1);
    const int mrow = b * NNODE + n;

    float acc[PER] = {};
    if (mask[mrow] != 0) {
        const int* rs = row_start + b * (NNODE + 1);
        const int s = rs[n], e = rs[n + 1];
        const unsigned long long* bk = bkt + (size_t)b * NEDGE;
        for (int i = s; i < e; ++i) {
            const unsigned long long pk = bk[i];
            const int u = (int)(pk & 0xffffffffu);
            const float w = __uint_as_float((unsigned)(pk >> 32));
            const _Float16* hr = H + ((size_t)(b * NNODE + u) * D) + lane * PER;
            if constexpr (PER == 4) {
                half4v hv = *(const half4v*)hr;
                #pragma unroll
                for (int j = 0; j < 4; ++j) acc[j] += w * (float)hv[j];
            } else {
                half2v hv = *(const half2v*)hr;
                #pragma unroll
                for (int j = 0; j < 2; ++j) acc[j] += w * (float)hv[j];
            }
        }
        #pragma unroll
        for (int j = 0; j < PER; ++j)
            acc[j] = fmaxf(acc[j] + bias[lane * PER + j], 0.0f);
    }

    OT* op = OUT + (size_t)mrow * D + lane * PER;
    if constexpr (PER == 4) {
        if constexpr (sizeof(OT) == 2) {
            half4v o = {(_Float16)acc[0], (_Float16)acc[1], (_Float16)acc[2], (_Float16)acc[3]};
            *(half4v*)op = o;
        } else {
            float4 o = {acc[0], acc[1], acc[2], acc[3]};
            *(float4*)op = o;
        }
    } else {
        if constexpr (sizeof(OT) == 2) {
            half2v o = {(_Float16)acc[0], (_Float16)acc[1]};
            *(half2v*)op = o;
        } else {
            float2 o = {acc[0], acc[1]};
            *(float2*)op = o;
        }
    }
}

extern "C" void kernel_launch(void* const* d_in, const int* in_sizes, int n_in,
                              void* d_out, int out_size, void* d_ws, size_t ws_size,
                              hipStream_t stream) {
    const float* x    = (const float*)d_in[0];
    const int*   ei   = (const int*)  d_in[1];
    const float* ew   = (const float*)d_in[2];
    const int*   mask = (const int*)  d_in[3];
    const float* W1   = (const float*)d_in[4];
    const float* b1   = (const float*)d_in[5];
    const float* W2   = (const float*)d_in[6];
    const float* b2   = (const float*)d_in[7];
    const float* W3   = (const float*)d_in[8];
    const float* b3   = (const float*)d_in[9];
    float* out = (float*)d_out;

    // Workspace layout (~89 MB), large-first for alignment:
    char* ws = (char*)d_ws;
    _Float16* X16  = (_Float16*)ws;                                   // 16 MB
    _Float16* H16  = (_Float16*)(ws + (16u << 20));                   // 32 MB
    _Float16* Act  = (_Float16*)(ws + (48u << 20));                   // 32 MB
    unsigned long long* bkt = (unsigned long long*)(ws + (80u << 20));// 8 MB
    _Float16* Wt1  = (_Float16*)(ws + (88u << 20));                   // 64 KB
    _Float16* Wt2  = Wt1 + 128 * 256;                                 // 128 KB
    _Float16* Wt3  = Wt2 + 256 * 256;                                 // 64 KB
    int* counts    = (int*)(Wt3 + 256 * 128);                         // 256 KB
    int* row_start = counts + BATCH * NNODE;
    int* cursor    = row_start + BATCH * (NNODE + 1);

    const dim3 blk(256);
    const int edgeBlocks   = BATCH * NEDGE / 256;   // 4096
    const int gatherBlocks = ROWS / 4;              // 16384

    // ---- CSR build (layer-invariant) ----
    hipMemsetAsync(counts, 0, (size_t)BATCH * NNODE * sizeof(int), stream);
    count_kernel<<<edgeBlocks, blk, 0, stream>>>(ei, mask, counts);
    scan_kernel<<<BATCH, blk, 0, stream>>>(counts, row_start, cursor);
    fill_kernel<<<edgeBlocks, blk, 0, stream>>>(ei, ew, mask, cursor, bkt);

    // ---- dtype prep ----
    cast_x_kernel<<<(ROWS * 128 / 4 + 255) / 256, blk, 0, stream>>>(x, X16, ROWS * 128 / 4);
    wt_kernel<<<(128 * 256 + 255) / 256, blk, 0, stream>>>(W1, Wt1, 128, 256);
    wt_kernel<<<(256 * 256 + 255) / 256, blk, 0, stream>>>(W2, Wt2, 256, 256);
    wt_kernel<<<(256 * 128 + 255) / 256, blk, 0, stream>>>(W3, Wt3, 256, 128);

    // ---- Layer 1: 128 -> 256 ----
    gemm_mfma<128><<<dim3(2, ROWS / 128), blk, 0, stream>>>(X16, Wt1, H16, 256);
    gather_kernel<256, _Float16><<<gatherBlocks, blk, 0, stream>>>(row_start, bkt, H16, mask, b1, Act);

    // ---- Layer 2: 256 -> 256 ----
    gemm_mfma<256><<<dim3(2, ROWS / 128), blk, 0, stream>>>(Act, Wt2, H16, 256);
    gather_kernel<256, _Float16><<<gatherBlocks, blk, 0, stream>>>(row_start, bkt, H16, mask, b2, Act);

    // ---- Layer 3: 256 -> 128 ----
    gemm_mfma<256><<<dim3(1, ROWS / 128), blk, 0, stream>>>(Act, Wt3, H16, 128);
    gather_kernel<128, float><<<gatherBlocks, blk, 0, stream>>>(row_start, bkt, H16, mask, b3, out);
}

// Round 4
// 262.135 us; speedup vs baseline: 9.8307x; 1.2076x over previous
//
#include <hip/hip_runtime.h>

static constexpr int BATCH = 16;
static constexpr int NNODE = 4096;
static constexpr int NEDGE = 65536;            // 1 << 16
static constexpr int ROWS  = BATCH * NNODE;    // 65536

typedef _Float16 half8  __attribute__((ext_vector_type(8)));
typedef _Float16 half4v __attribute__((ext_vector_type(4)));
typedef _Float16 half2v __attribute__((ext_vector_type(2)));
typedef float    f32x4  __attribute__((ext_vector_type(4)));

// ---------------- CSR build (once; reused by all 3 layers) ----------------

__global__ __launch_bounds__(256) void count_kernel(
    const int* __restrict__ ei, const int* __restrict__ mask,
    int* __restrict__ counts)
{
    const int idx = blockIdx.x * 256 + threadIdx.x;
    const int b = idx >> 16;
    const int e = idx & (NEDGE - 1);
    const int* eib = ei + (size_t)b * 2 * NEDGE;
    const int u = eib[e];
    const int v = eib[NEDGE + e];
    const int mrow = b * NNODE;
    if (mask[mrow + u] != 0 && mask[mrow + v] != 0)
        atomicAdd(&counts[mrow + v], 1);
}

__global__ __launch_bounds__(256) void scan_kernel(
    const int* __restrict__ counts, int* __restrict__ row_start,
    int* __restrict__ cursor)
{
    __shared__ int sums[256];
    const int b = blockIdx.x, t = threadIdx.x;
    const int* c = counts + b * NNODE;
    int* rs = row_start + b * (NNODE + 1);
    int* cu = cursor + b * NNODE;

    int local[16]; int s = 0;
    #pragma unroll
    for (int i = 0; i < 16; ++i) { local[i] = c[t * 16 + i]; s += local[i]; }
    sums[t] = s;
    __syncthreads();
    for (int off = 1; off < 256; off <<= 1) {
        int v = (t >= off) ? sums[t - off] : 0;
        __syncthreads();
        sums[t] += v;
        __syncthreads();
    }
    int run = (t == 0) ? 0 : sums[t - 1];
    #pragma unroll
    for (int i = 0; i < 16; ++i) { rs[t * 16 + i] = run; cu[t * 16 + i] = run; run += local[i]; }
    if (t == 255) rs[NNODE] = run;
}

__global__ __launch_bounds__(256) void fill_kernel(
    const int* __restrict__ ei, const float* __restrict__ ew,
    const int* __restrict__ mask, int* __restrict__ cursor,
    unsigned long long* __restrict__ bkt)
{
    const int idx = blockIdx.x * 256 + threadIdx.x;
    const int b = idx >> 16;
    const int e = idx & (NEDGE - 1);
    const int* eib = ei + (size_t)b * 2 * NEDGE;
    const int u = eib[e];
    const int v = eib[NEDGE + e];
    const int mrow = b * NNODE;
    if (mask[mrow + u] != 0 && mask[mrow + v] != 0) {
        const float w = ew[(size_t)b * NEDGE + e];
        const int pos = atomicAdd(&cursor[mrow + v], 1);
        bkt[(size_t)b * NEDGE + pos] =
            ((unsigned long long)__float_as_uint(w) << 32) | (unsigned)u;
    }
}

// ---------------- dtype prep ----------------

__global__ __launch_bounds__(256) void cast_x_kernel(
    const float* __restrict__ X, _Float16* __restrict__ X16, int n4)
{
    int i = blockIdx.x * 256 + threadIdx.x;
    if (i < n4) {
        float4 v = ((const float4*)X)[i];
        half4v h = {(_Float16)v.x, (_Float16)v.y, (_Float16)v.z, (_Float16)v.w};
        ((half4v*)X16)[i] = h;
    }
}

// W [K][Nd] fp32 -> Wt [Nd][K] fp16
__global__ __launch_bounds__(256) void wt_kernel(
    const float* __restrict__ W, _Float16* __restrict__ Wt, int K, int Nd)
{
    int i = blockIdx.x * 256 + threadIdx.x;
    if (i < K * Nd) {
        int k = i / Nd, n = i - k * Nd;
        Wt[n * K + k] = (_Float16)W[i];
    }
}

// ---------------- H = X @ Wt^T  (fp16 in, fp32 acc, fp16 out) ----------------
// 128x128 tile, BK=32, 4 waves of 64x64, mfma_f32_16x16x32_f16.
template<int K>
__global__ __launch_bounds__(256) void gemm_mfma(
    const _Float16* __restrict__ X,   // [M, K]
    const _Float16* __restrict__ Wt,  // [Nd, K]
    _Float16* __restrict__ H,         // [M, Nd]
    int Nd)
{
    __shared__ _Float16 As[128 * 32];   // [m][k] row-major
    __shared__ _Float16 Bs[128 * 32];   // [n][k] row-major

    const int tid  = threadIdx.x;
    const int lane = tid & 63;
    const int wave = tid >> 6;
    const int wr = wave >> 1, wc = wave & 1;
    const int quad = lane >> 4;
    const int l15  = lane & 15;

    const size_t bm = (size_t)blockIdx.y * 128;
    const int    bn = blockIdx.x * 128;

    f32x4 acc[4][4] = {};

    const int sr = tid >> 2;
    const int sc = (tid & 3) * 8;
    const _Float16* Ag0 = X  + (bm + sr) * K + sc;
    const _Float16* Ag1 = X  + (bm + 64 + sr) * K + sc;
    const _Float16* Bg0 = Wt + (size_t)(bn + sr) * K + sc;
    const _Float16* Bg1 = Wt + (size_t)(bn + 64 + sr) * K + sc;

    const _Float16* ap = As + (wr * 64 + l15) * 32 + quad * 8;
    const _Float16* bp = Bs + (wc * 64 + l15) * 32 + quad * 8;

    for (int k0 = 0; k0 < K; k0 += 32) {
        __builtin_amdgcn_global_load_lds(
            (const __attribute__((address_space(1))) void*)(Ag0 + k0),
            (__attribute__((address_space(3))) void*)(As + tid * 8), 16, 0, 0);
        __builtin_amdgcn_global_load_lds(
            (const __attribute__((address_space(1))) void*)(Ag1 + k0),
            (__attribute__((address_space(3))) void*)(As + 2048 + tid * 8), 16, 0, 0);
        __builtin_amdgcn_global_load_lds(
            (const __attribute__((address_space(1))) void*)(Bg0 + k0),
            (__attribute__((address_space(3))) void*)(Bs + tid * 8), 16, 0, 0);
        __builtin_amdgcn_global_load_lds(
            (const __attribute__((address_space(1))) void*)(Bg1 + k0),
            (__attribute__((address_space(3))) void*)(Bs + 2048 + tid * 8), 16, 0, 0);
        __syncthreads();

        half8 af[4], bf[4];
        #pragma unroll
        for (int mi = 0; mi < 4; ++mi) af[mi] = *(const half8*)(ap + mi * 16 * 32);
        #pragma unroll
        for (int ni = 0; ni < 4; ++ni) bf[ni] = *(const half8*)(bp + ni * 16 * 32);

        #pragma unroll
        for (int mi = 0; mi < 4; ++mi)
            #pragma unroll
            for (int ni = 0; ni < 4; ++ni)
                acc[mi][ni] = __builtin_amdgcn_mfma_f32_16x16x32_f16(
                    af[mi], bf[ni], acc[mi][ni], 0, 0, 0);
        __syncthreads();
    }

    // C/D layout: col = lane&15, row = quad*4 + r  [m89]
    const size_t rbase = bm + wr * 64 + quad * 4;
    const int    cbase = bn + wc * 64 + l15;
    #pragma unroll
    for (int mi = 0; mi < 4; ++mi)
        #pragma unroll
        for (int r = 0; r < 4; ++r) {
            size_t row = rbase + mi * 16 + r;
            #pragma unroll
            for (int ni = 0; ni < 4; ++ni)
                H[row * Nd + cbase + ni * 16] = (_Float16)acc[mi][ni][r];
        }
}

// ---------------- gather + bias + relu + mask (one wave per node) ----------
// 8-deep edge unroll: all 8 bkt entries come from one 64 B line; the 8 H-row
// loads are issued unconditionally (tail clamped to edge 0 with weight 0) so
// 8 independent loads are in flight per wave.
template<int D, typename OT>
__global__ __launch_bounds__(256) void gather_kernel(
    const int* __restrict__ row_start, const unsigned long long* __restrict__ bkt,
    const _Float16* __restrict__ H, const int* __restrict__ mask,
    const float* __restrict__ bias, OT* __restrict__ OUT)
{
    constexpr int PER = D / 64;
    const int gw   = blockIdx.x * 4 + (threadIdx.x >> 6);
    const int lane = threadIdx.x & 63;
    const int b = gw >> 12;
    const int n = gw & (NNODE - 1);
    const int mrow = b * NNODE + n;

    float acc[PER] = {};
    if (mask[mrow] != 0) {
        const int* rs = row_start + b * (NNODE + 1);
        const int s = rs[n], e = rs[n + 1];
        const unsigned long long* bk = bkt + (size_t)b * NEDGE;
        const _Float16* Hb = H + (size_t)b * NNODE * D + lane * PER;

        for (int i = s; i < e; i += 8) {
            const int cnt = e - i;   // >= 1
            unsigned long long pk[8];
            #pragma unroll
            for (int j = 0; j < 8; ++j) pk[j] = bk[i + j];   // slack-safe over-read

            const int u0 = (int)(pk[0] & 0xffffffffu);
            float wj[8];
            const _Float16* hp[8];
            #pragma unroll
            for (int j = 0; j < 8; ++j) {
                const bool ok = (j < cnt);
                const int u = ok ? (int)(pk[j] & 0xffffffffu) : u0;
                wj[j] = ok ? __uint_as_float((unsigned)(pk[j] >> 32)) : 0.0f;
                hp[j] = Hb + (size_t)u * D;
            }
            if constexpr (PER == 4) {
                half4v hv[8];
                #pragma unroll
                for (int j = 0; j < 8; ++j) hv[j] = *(const half4v*)hp[j];
                #pragma unroll
                for (int j = 0; j < 8; ++j)
                    #pragma unroll
                    for (int c = 0; c < 4; ++c) acc[c] += wj[j] * (float)hv[j][c];
            } else {
                half2v hv[8];
                #pragma unroll
                for (int j = 0; j < 8; ++j) hv[j] = *(const half2v*)hp[j];
                #pragma unroll
                for (int j = 0; j < 8; ++j)
                    #pragma unroll
                    for (int c = 0; c < 2; ++c) acc[c] += wj[j] * (float)hv[j][c];
            }
        }
        #pragma unroll
        for (int j = 0; j < PER; ++j)
            acc[j] = fmaxf(acc[j] + bias[lane * PER + j], 0.0f);
    }

    OT* op = OUT + (size_t)mrow * D + lane * PER;
    if constexpr (PER == 4) {
        if constexpr (sizeof(OT) == 2) {
            half4v o = {(_Float16)acc[0], (_Float16)acc[1], (_Float16)acc[2], (_Float16)acc[3]};
            *(half4v*)op = o;
        } else {
            float4 o = {acc[0], acc[1], acc[2], acc[3]};
            *(float4*)op = o;
        }
    } else {
        if constexpr (sizeof(OT) == 2) {
            half2v o = {(_Float16)acc[0], (_Float16)acc[1]};
            *(half2v*)op = o;
        } else {
            float2 o = {acc[0], acc[1]};
            *(float2*)op = o;
        }
    }
}

extern "C" void kernel_launch(void* const* d_in, const int* in_sizes, int n_in,
                              void* d_out, int out_size, void* d_ws, size_t ws_size,
                              hipStream_t stream) {
    const float* x    = (const float*)d_in[0];
    const int*   ei   = (const int*)  d_in[1];
    const float* ew   = (const float*)d_in[2];
    const int*   mask = (const int*)  d_in[3];
    const float* W1   = (const float*)d_in[4];
    const float* b1   = (const float*)d_in[5];
    const float* W2   = (const float*)d_in[6];
    const float* b2   = (const float*)d_in[7];
    const float* W3   = (const float*)d_in[8];
    const float* b3   = (const float*)d_in[9];
    float* out = (float*)d_out;

    // Workspace layout (~89 MB), large-first for alignment:
    char* ws = (char*)d_ws;
    _Float16* X16  = (_Float16*)ws;                                   // 16 MB
    _Float16* H16  = (_Float16*)(ws + (16u << 20));                   // 32 MB
    _Float16* Act  = (_Float16*)(ws + (48u << 20));                   // 32 MB
    unsigned long long* bkt = (unsigned long long*)(ws + (80u << 20));// 8 MB
    _Float16* Wt1  = (_Float16*)(ws + (88u << 20));                   // 64 KB
    _Float16* Wt2  = Wt1 + 128 * 256;                                 // 128 KB
    _Float16* Wt3  = Wt2 + 256 * 256;                                 // 64 KB
    int* counts    = (int*)(Wt3 + 256 * 128);                         // 256 KB
    int* row_start = counts + BATCH * NNODE;
    int* cursor    = row_start + BATCH * (NNODE + 1);

    const dim3 blk(256);
    const int edgeBlocks   = BATCH * NEDGE / 256;   // 4096
    const int gatherBlocks = ROWS / 4;              // 16384

    // ---- CSR build (layer-invariant) ----
    hipMemsetAsync(counts, 0, (size_t)BATCH * NNODE * sizeof(int), stream);
    count_kernel<<<edgeBlocks, blk, 0, stream>>>(ei, mask, counts);
    scan_kernel<<<BATCH, blk, 0, stream>>>(counts, row_start, cursor);
    fill_kernel<<<edgeBlocks, blk, 0, stream>>>(ei, ew, mask, cursor, bkt);

    // ---- dtype prep ----
    cast_x_kernel<<<(ROWS * 128 / 4 + 255) / 256, blk, 0, stream>>>(x, X16, ROWS * 128 / 4);
    wt_kernel<<<(128 * 256 + 255) / 256, blk, 0, stream>>>(W1, Wt1, 128, 256);
    wt_kernel<<<(256 * 256 + 255) / 256, blk, 0, stream>>>(W2, Wt2, 256, 256);
    wt_kernel<<<(256 * 128 + 255) / 256, blk, 0, stream>>>(W3, Wt3, 256, 128);

    // ---- Layer 1: 128 -> 256 ----
    gemm_mfma<128><<<dim3(2, ROWS / 128), blk, 0, stream>>>(X16, Wt1, H16, 256);
    gather_kernel<256, _Float16><<<gatherBlocks, blk, 0, stream>>>(row_start, bkt, H16, mask, b1, Act);

    // ---- Layer 2: 256 -> 256 ----
    gemm_mfma<256><<<dim3(2, ROWS / 128), blk, 0, stream>>>(Act, Wt2, H16, 256);
    gather_kernel<256, _Float16><<<gatherBlocks, blk, 0, stream>>>(row_start, bkt, H16, mask, b2, Act);

    // ---- Layer 3: 256 -> 128 ----
    gemm_mfma<256><<<dim3(1, ROWS / 128), blk, 0, stream>>>(Act, Wt3, H16, 128);
    gather_kernel<128, float><<<gatherBlocks, blk, 0, stream>>>(row_start, bkt, H16, mask, b3, out);
}